// Round 18
// baseline (41.270 us; speedup 1.0000x reference)
//
#include <hip/hip_runtime.h>
#include <hip/hip_bf16.h>

typedef __attribute__((ext_vector_type(8))) short bf16x8;
typedef __attribute__((ext_vector_type(4))) float f32x4;

#define NROWS 8192
#define EMB   512
#define NCLS  98
#define NCPAD 128
#define MAXPER 256
#define NBLK  (NROWS / 32)            // 256 main blocks
#define ALPHA_F 10.0f
#define BETA_F  2.0f

__device__ __forceinline__ unsigned short f2bf(float x) {
    unsigned u = __builtin_bit_cast(unsigned, x);
    u += 0x7FFF + ((u >> 16) & 1);
    return (unsigned short)(u >> 16);
}

__device__ __forceinline__ void g2l16(const void* g, void* l) {
    __builtin_amdgcn_global_load_lds(
        (const __attribute__((address_space(1))) unsigned int*)g,
        (__attribute__((address_space(3))) unsigned int*)l, 16, 0, 0);
}

// ---------------- init: block 0 = zero+scatter; blocks 1..8 = kprep (16 classes each) ----
__global__ __launch_bounds__(1024) void init_scatter_kernel(
        const int* __restrict__ T, const float* __restrict__ K,
        int* __restrict__ cnt, int* __restrict__ bucket,
        unsigned int* __restrict__ ctr, float* __restrict__ usum,
        unsigned short* __restrict__ KbT) {
    const int tid = threadIdx.x;
    const int lane = tid & 63, w = tid >> 6;
    const int bx = blockIdx.x;

    if (bx > 0) {
        // kprep: KbT[c][k] = bf16(K[k][c]/||K[:,c]||), 16 waves -> 16 classes per block
        int c = (bx - 1) * 16 + w;             // 0..127
        if (c < NCLS) {
            float v[8]; float s = 0.f;
            #pragma unroll
            for (int q = 0; q < 8; ++q) {
                float x = K[(size_t)(lane + q * 64) * NCLS + c];
                v[q] = x; s = fmaf(x, x, s);
            }
            #pragma unroll
            for (int dd = 32; dd > 0; dd >>= 1) s += __shfl_xor(s, dd);
            float inv = 1.0f / sqrtf(s);
            #pragma unroll
            for (int q = 0; q < 8; ++q)
                KbT[(size_t)c * EMB + lane + q * 64] = f2bf(v[q] * inv);
        } else {
            #pragma unroll
            for (int q = 0; q < 8; ++q)
                KbT[(size_t)c * EMB + lane + q * 64] = 0;
        }
        return;
    }

    __shared__ int lh[NCLS];
    if (tid < NCLS) lh[tid] = 0;
    if (tid == 0) *ctr = 0;
    if (tid < EMB) usum[tid] = 0.f;
    __syncthreads();
    #pragma unroll
    for (int k = 0; k < NROWS / 1024; ++k) {
        int i = k * 1024 + tid;
        int t = T[i];
        int slot = atomicAdd(&lh[t], 1);
        if (slot < MAXPER) bucket[t * MAXPER + slot] = i;
    }
    __syncthreads();
    if (tid < NCLS) cnt[tid] = lh[tid];
}

// ---------------- V[c][k] = bucket-sum of X (8 waves); usum accumulated ----------
__global__ __launch_bounds__(512) void classv_kernel(
        const float* __restrict__ X,
        const int* __restrict__ cnt, const int* __restrict__ bucket,
        float* __restrict__ V, float* __restrict__ usum) {
    const int tid = threadIdx.x;
    const int lane = tid & 63, w = tid >> 6;
    const int bx = blockIdx.x;

    __shared__ float red[7][64];
    const int c = bx >> 3, d0 = (bx & 7) * 64;
    int n = cnt[c]; if (n > MAXPER) n = MAXPER;
    const int* bk = bucket + c * MAXPER;
    float a = 0.f;
    for (int j = w; j < n; j += 8) {
        int row = bk[j];
        a += X[(size_t)row * EMB + d0 + lane];
    }
    if (w > 0) red[w - 1][lane] = a;
    __syncthreads();
    if (w == 0) {
        #pragma unroll
        for (int q = 0; q < 7; ++q) a += red[q][lane];
        V[(size_t)c * EMB + d0 + lane] = a;
        atomicAdd(&usum[d0 + lane], a);
    }
}

// ---------------- main: 32 rows/block, 8 waves, dbuf K-loop with async-split staging ----
__global__ __launch_bounds__(512) void main_gemm(
        const float* __restrict__ X, const unsigned short* __restrict__ KbT,
        const int* __restrict__ T, const int* __restrict__ cnt,
        const float* __restrict__ V, const float* __restrict__ usum,
        double* __restrict__ partials, unsigned int* __restrict__ ctr,
        float* __restrict__ out) {
    __shared__ unsigned short As[2][32 * 64];    // 8 KB bf16
    __shared__ unsigned short Bs[2][NCPAD * 64]; // 32 KB bf16
    __shared__ float P[32][NCPAD];               // 16 KB logits
    __shared__ int   trow[32];
    __shared__ double redacc[8][4];
    __shared__ int   lastflag;

    const int tid = threadIdx.x;
    const int w = tid >> 6, lane = tid & 63;
    const int row0 = blockIdx.x * 32;
    const int wr = w & 1, wc = w >> 1;        // 2 row-tiles x 4 col-tiles
    const int c0 = lane & 15, g = lane >> 4;

    // A-staging mapping doubles as row-stat ownership: 16 threads per row, float4 each
    const int ar = tid >> 4, ak = (tid & 15) * 4;
    const int myt = T[row0 + ar];
    if (tid < 32) trow[tid] = T[row0 + tid];
    const float* vrow = V + (size_t)myt * EMB;

    float s = 0.f, sm = 0.f; double d = 0.0;
    f32x4 av[2] = {};

    // ---- prologue: stage kk=0 into buffer 0 (stats for chunk 0 ride along) ----
    {
        const float* xp = X + (size_t)(row0 + ar) * EMB + ak;
        float4 xa = *(const float4*)xp;
        float4 ua = *(const float4*)(usum + ak);
        float4 va = *(const float4*)(vrow + ak);
        float xf[4] = {xa.x, xa.y, xa.z, xa.w};
        float uf[4] = {ua.x, ua.y, ua.z, ua.w};
        float vf[4] = {va.x, va.y, va.z, va.w};
        unsigned short ab[4];
        #pragma unroll
        for (int q = 0; q < 4; ++q) {
            s  = fmaf(xf[q], uf[q], s);
            sm = fmaf(xf[q], vf[q], sm);
            d  = fma((double)xf[q], (double)xf[q], d);
            ab[q] = f2bf(xf[q]);
        }
        *(ushort4*)&As[0][ar * 64 + ak] = make_ushort4(ab[0], ab[1], ab[2], ab[3]);
        #pragma unroll
        for (int q = 0; q < 2; ++q) {
            int lb = q * 8192 + tid * 16;
            int c = lb >> 7, kb = lb & 127;
            g2l16((const char*)KbT + (size_t)c * 1024 + kb, (char*)&Bs[0][0] + lb);
        }
        __syncthreads();   // buffer 0 ready (vmcnt drained by compiler)
    }

    // ---- main loop: issue loads early, MFMA, then consume loads (T14 split) ----
    for (int it = 0; it < 8; ++it) {
        const int buf = it & 1;
        float4 xa, ua, va;
        if (it < 7) {
            const int kn = (it + 1) * 64;
            xa = *(const float4*)(X + (size_t)(row0 + ar) * EMB + kn + ak);
            ua = *(const float4*)(usum + kn + ak);
            va = *(const float4*)(vrow + kn + ak);
            #pragma unroll
            for (int q = 0; q < 2; ++q) {    // B prefetch: in flight during MFMA below
                int lb = q * 8192 + tid * 16;
                int c = lb >> 7, kb = lb & 127;
                g2l16((const char*)KbT + (size_t)c * 1024 + kn * 2 + kb,
                      (char*)&Bs[buf ^ 1][0] + lb);
            }
        }
        #pragma unroll
        for (int ks = 0; ks < 2; ++ks) {
            bf16x8 a = *(const bf16x8*)&As[buf][(wr * 16 + c0) * 64 + ks * 32 + g * 8];
            #pragma unroll
            for (int ni = 0; ni < 2; ++ni) {
                bf16x8 b = *(const bf16x8*)&Bs[buf][(wc * 32 + ni * 16 + c0) * 64 + ks * 32 + g * 8];
                av[ni] = __builtin_amdgcn_mfma_f32_16x16x32_bf16(a, b, av[ni], 0, 0, 0);
            }
        }
        if (it < 7) {                        // consume loads after MFMA (latency hidden)
            float xf[4] = {xa.x, xa.y, xa.z, xa.w};
            float uf[4] = {ua.x, ua.y, ua.z, ua.w};
            float vf[4] = {va.x, va.y, va.z, va.w};
            unsigned short ab[4];
            #pragma unroll
            for (int q = 0; q < 4; ++q) {
                s  = fmaf(xf[q], uf[q], s);
                sm = fmaf(xf[q], vf[q], sm);
                d  = fma((double)xf[q], (double)xf[q], d);
                ab[q] = f2bf(xf[q]);
            }
            *(ushort4*)&As[buf ^ 1][ar * 64 + ak] = make_ushort4(ab[0], ab[1], ab[2], ab[3]);
        }
        __syncthreads();   // buf^1 writes visible; all reads of buf done
    }

    // ---- row stats: reduce over the 16 threads sharing a row, then pos/neg ----
    #pragma unroll
    for (int m = 1; m < 16; m <<= 1) {
        s += __shfl_xor(s, m); sm += __shfl_xor(sm, m); d += __shfl_xor(d, m);
    }
    double pc = 0.0, nc = 0.0;
    if ((lane & 15) == 0) {
        int h = cnt[myt];
        float pos_sum; int pos_cnt;
        if (d < 1.0) { pos_sum = sm;            pos_cnt = h;     }
        else         { pos_sum = sm - (float)d; pos_cnt = h - 1; }
        float neg_sum = s - sm;
        pc = (double)(pos_sum / (float)pos_cnt);
        nc = (double)(neg_sum / (float)(NROWS - h));
    }
    #pragma unroll
    for (int m = 1; m < 64; m <<= 1) { pc += __shfl_xor(pc, m); nc += __shfl_xor(nc, m); }

    // ---- dump logits to LDS (C-map: row = g*4+reg, col = c0) ----
    #pragma unroll
    for (int ni = 0; ni < 2; ++ni)
        #pragma unroll
        for (int r = 0; r < 4; ++r)
            P[wr * 16 + g * 4 + r][wc * 32 + ni * 16 + c0] = av[ni][r];
    __syncthreads();

    // ---- softmax / argmax / loss, 4 rows per wave ----
    float lossacc = 0.f, pracc = 0.f;
    #pragma unroll
    for (int j = 0; j < 4; ++j) {
        const int rl = w * 4 + j;
        const int tgt = trow[rl];
        float l1 = P[rl][lane], l2 = P[rl][lane + 64];
        {
            float cos1 = fminf(1.f, fmaxf(-1.f, l1));
            float cos2 = fminf(1.f, fmaxf(-1.f, l2));
            l1 = (cos1 - (lane == tgt ? BETA_F : 0.f)) * ALPHA_F;
            l2 = (cos2 - (lane + 64 == tgt ? BETA_F : 0.f)) * ALPHA_F;
            if (lane      >= NCLS) l1 = -1e30f;
            if (lane + 64 >= NCLS) l2 = -1e30f;
        }
        float m = fmaxf(l1, l2);
        #pragma unroll
        for (int dd = 1; dd < 64; dd <<= 1) m = fmaxf(m, __shfl_xor(m, dd));
        float se = (lane < NCLS ? __expf(l1 - m) : 0.f)
                 + (lane + 64 < NCLS ? __expf(l2 - m) : 0.f);
        float tval = (lane == tgt) ? l1 : ((lane + 64 == tgt) ? l2 : -1e30f);
        float bv; int bi;
        if (l2 > l1) { bv = l2; bi = lane + 64; } else { bv = l1; bi = lane; }
        #pragma unroll
        for (int dd = 1; dd < 64; dd <<= 1) {
            se += __shfl_xor(se, dd);
            tval = fmaxf(tval, __shfl_xor(tval, dd));
            float ov = __shfl_xor(bv, dd); int oi = __shfl_xor(bi, dd);
            if (ov > bv || (ov == bv && oi < bi)) { bv = ov; bi = oi; }
        }
        lossacc += (m + logf(se)) - tval;
        pracc   += (bi == tgt) ? 1.f : 0.f;
    }

    // ---- block reduce; last finishing block reduces all partials and writes d_out ----
    if (lane == 0) {
        redacc[w][0] = (double)lossacc;
        redacc[w][1] = (double)pracc;
        redacc[w][2] = pc;
        redacc[w][3] = nc;
    }
    __syncthreads();
    if (tid == 0) {
        const int bx = blockIdx.x;
        double a0 = 0.0, a1 = 0.0, a2 = 0.0, a3 = 0.0;
        #pragma unroll
        for (int ww = 0; ww < 8; ++ww) {
            a0 += redacc[ww][0]; a1 += redacc[ww][1];
            a2 += redacc[ww][2]; a3 += redacc[ww][3];
        }
        partials[bx * 4 + 0] = a0;
        partials[bx * 4 + 1] = a1;
        partials[bx * 4 + 2] = a2;
        partials[bx * 4 + 3] = a3;
        __threadfence();
        lastflag = (atomicAdd(ctr, 1u) == NBLK - 1) ? 1 : 0;
    }
    __syncthreads();
    if (lastflag && w == 0) {
        __threadfence();
        double a0 = 0.0, a1 = 0.0, a2 = 0.0, a3 = 0.0;
        for (int i = lane; i < NBLK; i += 64) {
            a0 += partials[i * 4 + 0];
            a1 += partials[i * 4 + 1];
            a2 += partials[i * 4 + 2];
            a3 += partials[i * 4 + 3];
        }
        #pragma unroll
        for (int m = 1; m < 64; m <<= 1) {
            a0 += __shfl_xor(a0, m); a1 += __shfl_xor(a1, m);
            a2 += __shfl_xor(a2, m); a3 += __shfl_xor(a3, m);
        }
        if (lane == 0) {
            out[0] = (float)(a0 / NROWS);
            out[1] = (float)(a1 / NROWS);
            out[2] = (float)(a2 / NROWS);
            out[3] = (float)(a3 / NROWS);
        }
    }
}

// ================= fallback f32 path (tiny workspace) =================
#define BM 64
#define BN 64
#define BK 32
#define LDA 68

__global__ void hist_kernel(const int* __restrict__ t, int* __restrict__ hist) {
    int i = blockIdx.x * blockDim.x + threadIdx.x;
    if (i < NROWS) atomicAdd(&hist[t[i]], 1);
}

__global__ void colnorm_kernel(const float* __restrict__ K, float* __restrict__ colinv) {
    int c = blockIdx.x;
    float s = 0.f;
    for (int k = threadIdx.x; k < EMB; k += 64) {
        float v = K[k * NCLS + c];
        s = fmaf(v, v, s);
    }
    #pragma unroll
    for (int off = 32; off > 0; off >>= 1) s += __shfl_down(s, off);
    if (threadIdx.x == 0) colinv[c] = 1.0f / sqrtf(s);
}

__global__ __launch_bounds__(256) void simred_kernel(
        const float* __restrict__ X, const int* __restrict__ T,
        float* __restrict__ S, float* __restrict__ SAME) {
    __shared__ float As[BK * LDA];
    __shared__ float Bs[BK * LDA];
    __shared__ int   trow[BM], tcol[BN];
    __shared__ float redS[BM], redSame[BM];

    const int tid = threadIdx.x;
    const int tx = tid & 15, ty = tid >> 4;
    const int i0 = blockIdx.x * BM, j0 = blockIdx.y * BN;

    if (tid < BM) {
        trow[tid] = T[i0 + tid];
        tcol[tid] = T[j0 + tid];
        redS[tid] = 0.f;
        redSame[tid] = 0.f;
    }

    float c[4][4] = {};
    for (int kk = 0; kk < EMB; kk += BK) {
        #pragma unroll
        for (int q = 0; q < 2; ++q) {
            int l  = tid * 2 + q;
            int r  = l >> 3;
            int kq = (l & 7) << 2;
            const float4 va = *(const float4*)(X + (size_t)(i0 + r) * EMB + kk + kq);
            As[(kq + 0) * LDA + r] = va.x;
            As[(kq + 1) * LDA + r] = va.y;
            As[(kq + 2) * LDA + r] = va.z;
            As[(kq + 3) * LDA + r] = va.w;
            const float4 vb = *(const float4*)(X + (size_t)(j0 + r) * EMB + kk + kq);
            Bs[(kq + 0) * LDA + r] = vb.x;
            Bs[(kq + 1) * LDA + r] = vb.y;
            Bs[(kq + 2) * LDA + r] = vb.z;
            Bs[(kq + 3) * LDA + r] = vb.w;
        }
        __syncthreads();
        #pragma unroll
        for (int k = 0; k < BK; ++k) {
            float4 a4 = *(const float4*)&As[k * LDA + ty * 4];
            float4 b4 = *(const float4*)&Bs[k * LDA + tx * 4];
            float a[4] = {a4.x, a4.y, a4.z, a4.w};
            float b[4] = {b4.x, b4.y, b4.z, b4.w};
            #pragma unroll
            for (int i = 0; i < 4; ++i)
                #pragma unroll
                for (int j = 0; j < 4; ++j)
                    c[i][j] = fmaf(a[i], b[j], c[i][j]);
        }
        __syncthreads();
    }

    #pragma unroll
    for (int i = 0; i < 4; ++i) {
        int r = ty * 4 + i;
        int tr = trow[r];
        float s = 0.f, sm = 0.f;
        #pragma unroll
        for (int j = 0; j < 4; ++j) {
            float v = c[i][j];
            s += v;
            if (tcol[tx * 4 + j] == tr) sm += v;
        }
        atomicAdd(&redS[r], s);
        atomicAdd(&redSame[r], sm);
    }
    __syncthreads();
    if (tid < BM) {
        atomicAdd(&S[i0 + tid],    redS[tid]);
        atomicAdd(&SAME[i0 + tid], redSame[tid]);
    }
}

__global__ __launch_bounds__(128) void loss_kernel(
        const float* __restrict__ X, const int* __restrict__ T,
        const float* __restrict__ K, const float* __restrict__ colinv,
        double* __restrict__ acc) {
    const int row = blockIdx.x;
    const int tid = threadIdx.x;
    __shared__ float xs[EMB];
    *(float4*)&xs[tid * 4] = *(const float4*)&X[(size_t)row * EMB + tid * 4];
    __syncthreads();

    const int tgt = T[row];
    const int c = tid;
    float logit = -1e30f;
    if (c < NCLS) {
        float d = 0.f;
        #pragma unroll 4
        for (int k = 0; k < EMB; ++k) d = fmaf(K[k * NCLS + c], xs[k], d);
        float cosv = d * colinv[c];
        cosv = fminf(1.f, fmaxf(-1.f, cosv));
        logit = (cosv - (c == tgt ? BETA_F : 0.f)) * ALPHA_F;
    }

    __shared__ float rv[128];
    __shared__ int   ri[128];
    __shared__ float Lt;
    if (c == tgt) Lt = logit;

    rv[tid] = logit;
    __syncthreads();
    #pragma unroll
    for (int s = 64; s > 0; s >>= 1) {
        if (tid < s) rv[tid] = fmaxf(rv[tid], rv[tid + s]);
        __syncthreads();
    }
    const float m = rv[0];
    __syncthreads();

    rv[tid] = (c < NCLS) ? expf(logit - m) : 0.f;
    __syncthreads();
    #pragma unroll
    for (int s = 64; s > 0; s >>= 1) {
        if (tid < s) rv[tid] += rv[tid + s];
        __syncthreads();
    }
    const float lse = m + logf(rv[0]);
    __syncthreads();

    rv[tid] = logit;
    ri[tid] = (c < NCLS) ? c : 0x7fffffff;
    __syncthreads();
    #pragma unroll
    for (int s = 64; s > 0; s >>= 1) {
        if (tid < s) {
            float vo = rv[tid + s]; int io = ri[tid + s];
            if (vo > rv[tid] || (vo == rv[tid] && io < ri[tid])) { rv[tid] = vo; ri[tid] = io; }
        }
        __syncthreads();
    }

    if (tid == 0) {
        float loss_i = lse - Lt;
        atomicAdd(&acc[0], (double)loss_i);
        atomicAdd(&acc[1], (ri[0] == tgt) ? 1.0 : 0.0);
    }
}

__global__ void finalize_kernel(
        const float* __restrict__ X, const int* __restrict__ T,
        const int* __restrict__ hist, const float* __restrict__ S,
        const float* __restrict__ SAME, double* __restrict__ acc) {
    int r = blockIdx.x * blockDim.x + threadIdx.x;
    if (r >= NROWS) return;
    const float* x = X + (size_t)r * EMB;
    double d = 0.0;
    for (int k = 0; k < EMB; ++k) d = fma((double)x[k], (double)x[k], d);
    int h = hist[T[r]];
    float same = SAME[r];
    float pos_sum; int pos_cnt;
    if (d < 1.0) { pos_sum = same;            pos_cnt = h;     }
    else         { pos_sum = same - (float)d; pos_cnt = h - 1; }
    float neg_sum = S[r] - same;
    int   neg_cnt = NROWS - h;
    atomicAdd(&acc[2], (double)(pos_sum / (float)pos_cnt));
    atomicAdd(&acc[3], (double)(neg_sum / (float)neg_cnt));
}

__global__ void out_kernel(const double* __restrict__ acc, float* __restrict__ out) {
    if (threadIdx.x == 0) {
        out[0] = (float)(acc[0] / NROWS);
        out[1] = (float)(acc[1] / NROWS);
        out[2] = (float)(acc[2] / NROWS);
        out[3] = (float)(acc[3] / NROWS);
    }
}

extern "C" void kernel_launch(void* const* d_in, const int* in_sizes, int n_in,
                              void* d_out, int out_size, void* d_ws, size_t ws_size,
                              hipStream_t stream) {
    const float* X = (const float*)d_in[0];   // [8192, 512]
    const int*   T = (const int*)d_in[1];     // [8192]
    const float* K = (const float*)d_in[2];   // [512, 98]
    float* out = (float*)d_out;               // 4 scalars

    const size_t KBT_BYTES    = (size_t)NCPAD * EMB * sizeof(unsigned short); // 128 KB
    const size_t V_BYTES      = (size_t)NCLS * EMB * sizeof(float);           // 200704 B
    const size_t BUCKET_BYTES = (size_t)NCLS * MAXPER * sizeof(int);          // 100352 B
    const size_t PART_BYTES   = (size_t)NBLK * 4 * sizeof(double);            // 8 KB
    const size_t MISC_BYTES   = 128 * sizeof(int) + 64 + 512 * sizeof(float); // cnt+ctr+usum

    if (ws_size >= KBT_BYTES + V_BYTES + BUCKET_BYTES + PART_BYTES + MISC_BYTES + 256) {
        unsigned short* KbT = (unsigned short*)d_ws;
        float*  V        = (float*)((char*)d_ws + KBT_BYTES);
        int*    bucket   = (int*)((char*)d_ws + KBT_BYTES + V_BYTES);
        double* partials = (double*)((char*)d_ws + KBT_BYTES + V_BYTES + BUCKET_BYTES);
        int*    cnt      = (int*)((char*)partials + PART_BYTES);
        unsigned int* ctr = (unsigned int*)(cnt + 128);
        float*  usum     = (float*)(ctr + 16);

        init_scatter_kernel<<<9, 1024, 0, stream>>>(T, K, cnt, bucket, ctr, usum, KbT);
        classv_kernel<<<784, 512, 0, stream>>>(X, cnt, bucket, V, usum);
        main_gemm<<<NBLK, 512, 0, stream>>>(X, KbT, T, cnt, V, usum, partials, ctr, out);
    } else {
        // fallback: f32 path (small workspace)
        const size_t FB_BYTES = sizeof(double) * 4 + sizeof(int) * NCLS
                              + sizeof(float) * (NCLS + 2 * NROWS);
        double* acc    = (double*)d_ws;
        int*    hist   = (int*)(acc + 4);
        float*  colinv = (float*)(hist + NCLS);
        float*  S      = colinv + NCLS;
        float*  SAME   = S + NROWS;

        hipMemsetAsync(d_ws, 0, FB_BYTES, stream);
        hist_kernel<<<(NROWS + 255) / 256, 256, 0, stream>>>(T, hist);
        colnorm_kernel<<<NCLS, 64, 0, stream>>>(K, colinv);
        simred_kernel<<<dim3(NROWS / BM, NROWS / BN), 256, 0, stream>>>(X, T, S, SAME);
        loss_kernel<<<NROWS, 128, 0, stream>>>(X, T, K, colinv, acc);
        finalize_kernel<<<(NROWS + 255) / 256, 256, 0, stream>>>(X, T, hist, S, SAME, acc);
        out_kernel<<<1, 64, 0, stream>>>(acc, out);
    }
}

// Round 19
// 40.480 us; speedup vs baseline: 1.0195x; 1.0195x over previous
//
#include <hip/hip_runtime.h>
#include <hip/hip_bf16.h>

typedef __attribute__((ext_vector_type(8))) short bf16x8;
typedef __attribute__((ext_vector_type(4))) float f32x4;

#define NROWS 8192
#define EMB   512
#define NCLS  98
#define NCPAD 128
#define MAXPER 256
#define NBLK  (NROWS / 32)            // 256 main blocks
#define ALPHA_F 10.0f
#define BETA_F  2.0f

__device__ __forceinline__ unsigned short f2bf(float x) {
    unsigned u = __builtin_bit_cast(unsigned, x);
    u += 0x7FFF + ((u >> 16) & 1);
    return (unsigned short)(u >> 16);
}

__device__ __forceinline__ void g2l16(const void* g, void* l) {
    __builtin_amdgcn_global_load_lds(
        (const __attribute__((address_space(1))) unsigned int*)g,
        (__attribute__((address_space(3))) unsigned int*)l, 16, 0, 0);
}

// ---------------- single-block: zero ctr/usum + counting-sort scatter ----------------
__global__ __launch_bounds__(1024) void init_scatter_kernel(
        const int* __restrict__ T, int* __restrict__ cnt, int* __restrict__ bucket,
        unsigned int* __restrict__ ctr, float* __restrict__ usum) {
    __shared__ int lh[NCLS];
    const int tid = threadIdx.x;
    if (tid < NCLS) lh[tid] = 0;
    if (tid == 0) *ctr = 0;
    if (tid < EMB) usum[tid] = 0.f;
    __syncthreads();
    #pragma unroll
    for (int k = 0; k < NROWS / 1024; ++k) {
        int i = k * 1024 + tid;
        int t = T[i];
        int slot = atomicAdd(&lh[t], 1);
        if (slot < MAXPER) bucket[t * MAXPER + slot] = i;
    }
    __syncthreads();
    if (tid < NCLS) cnt[tid] = lh[tid];
}

// ---------------- V[c][k] = bucket-sum of X (8 waves); usum accumulated; kprep ----------
__global__ __launch_bounds__(512) void classv_kernel(
        const float* __restrict__ X, const float* __restrict__ K,
        const int* __restrict__ cnt, const int* __restrict__ bucket,
        float* __restrict__ V, float* __restrict__ usum,
        unsigned short* __restrict__ KbT) {
    const int tid = threadIdx.x;
    const int lane = tid & 63, w = tid >> 6;
    const int bx = blockIdx.x;

    if (bx >= 784) {
        int c = (bx - 784) * 8 + w;            // 0..127
        if (c < NCLS) {
            float v[8]; float s = 0.f;
            #pragma unroll
            for (int q = 0; q < 8; ++q) {
                float x = K[(size_t)(lane + q * 64) * NCLS + c];
                v[q] = x; s = fmaf(x, x, s);
            }
            #pragma unroll
            for (int d = 32; d > 0; d >>= 1) s += __shfl_xor(s, d);
            float inv = 1.0f / sqrtf(s);
            #pragma unroll
            for (int q = 0; q < 8; ++q)
                KbT[(size_t)c * EMB + lane + q * 64] = f2bf(v[q] * inv);
        } else {
            #pragma unroll
            for (int q = 0; q < 8; ++q)
                KbT[(size_t)c * EMB + lane + q * 64] = 0;
        }
        return;
    }

    __shared__ float red[7][64];
    const int c = bx >> 3, d0 = (bx & 7) * 64;
    int n = cnt[c]; if (n > MAXPER) n = MAXPER;
    const int* bk = bucket + c * MAXPER;
    float a = 0.f;
    for (int j = w; j < n; j += 8) {
        int row = bk[j];
        a += X[(size_t)row * EMB + d0 + lane];
    }
    if (w > 0) red[w - 1][lane] = a;
    __syncthreads();
    if (w == 0) {
        #pragma unroll
        for (int q = 0; q < 7; ++q) a += red[q][lane];
        V[(size_t)c * EMB + d0 + lane] = a;
        atomicAdd(&usum[d0 + lane], a);
    }
}

// ---------------- main: 32 rows/block, 8 waves, double-buffered K-loop ----------
__global__ __launch_bounds__(512) void main_gemm(
        const float* __restrict__ X, const unsigned short* __restrict__ KbT,
        const int* __restrict__ T, const int* __restrict__ cnt,
        const float* __restrict__ V, const float* __restrict__ usum,
        double* __restrict__ partials, unsigned int* __restrict__ ctr,
        float* __restrict__ out) {
    __shared__ unsigned short As[2][32 * 64];    // 8 KB bf16
    __shared__ unsigned short Bs[2][NCPAD * 64]; // 32 KB bf16
    __shared__ float P[32][NCPAD];               // 16 KB logits
    __shared__ int   trow[32];
    __shared__ double redacc[8][4];
    __shared__ int   lastflag;

    const int tid = threadIdx.x;
    const int w = tid >> 6, lane = tid & 63;
    const int row0 = blockIdx.x * 32;
    const int wr = w & 1, wc = w >> 1;        // 2 row-tiles x 4 col-tiles
    const int c0 = lane & 15, g = lane >> 4;

    // A-staging mapping doubles as row-stat ownership: 16 threads per row, float4 each
    const int ar = tid >> 4, ak = (tid & 15) * 4;
    const int myt = T[row0 + ar];
    if (tid < 32) trow[tid] = T[row0 + tid];
    const float* vrow = V + (size_t)myt * EMB;

    float s = 0.f, sm = 0.f; double d = 0.0;
    f32x4 av[2] = {};

    // ---- prologue: stage kk=0 into buffer 0 (stats for chunk 0 ride along) ----
    {
        const float* xp = X + (size_t)(row0 + ar) * EMB + ak;
        float4 xa = *(const float4*)xp;
        float4 ua = *(const float4*)(usum + ak);
        float4 va = *(const float4*)(vrow + ak);
        float xf[4] = {xa.x, xa.y, xa.z, xa.w};
        float uf[4] = {ua.x, ua.y, ua.z, ua.w};
        float vf[4] = {va.x, va.y, va.z, va.w};
        unsigned short ab[4];
        #pragma unroll
        for (int q = 0; q < 4; ++q) {
            s  = fmaf(xf[q], uf[q], s);
            sm = fmaf(xf[q], vf[q], sm);
            d  = fma((double)xf[q], (double)xf[q], d);
            ab[q] = f2bf(xf[q]);
        }
        *(ushort4*)&As[0][ar * 64 + ak] = make_ushort4(ab[0], ab[1], ab[2], ab[3]);
        #pragma unroll
        for (int q = 0; q < 2; ++q) {
            int lb = q * 8192 + tid * 16;
            int c = lb >> 7, kb = lb & 127;
            g2l16((const char*)KbT + (size_t)c * 1024 + kb, (char*)&Bs[0][0] + lb);
        }
        __syncthreads();   // buffer 0 ready (vmcnt drained by compiler)
    }

    // ---- main loop: 8 K-steps, prefetch k+1 into buf^1, one barrier per step ----
    for (int it = 0; it < 8; ++it) {
        const int buf = it & 1;
        if (it < 7) {
            const int kn = (it + 1) * 64;
            const float* xp = X + (size_t)(row0 + ar) * EMB + kn + ak;
            float4 xa = *(const float4*)xp;
            float4 ua = *(const float4*)(usum + kn + ak);
            float4 va = *(const float4*)(vrow + kn + ak);
            float xf[4] = {xa.x, xa.y, xa.z, xa.w};
            float uf[4] = {ua.x, ua.y, ua.z, ua.w};
            float vf[4] = {va.x, va.y, va.z, va.w};
            unsigned short ab[4];
            #pragma unroll
            for (int q = 0; q < 4; ++q) {
                s  = fmaf(xf[q], uf[q], s);
                sm = fmaf(xf[q], vf[q], sm);
                d  = fma((double)xf[q], (double)xf[q], d);
                ab[q] = f2bf(xf[q]);
            }
            *(ushort4*)&As[buf ^ 1][ar * 64 + ak] = make_ushort4(ab[0], ab[1], ab[2], ab[3]);
            #pragma unroll
            for (int q = 0; q < 2; ++q) {    // B prefetch: in flight during MFMA below
                int lb = q * 8192 + tid * 16;
                int c = lb >> 7, kb = lb & 127;
                g2l16((const char*)KbT + (size_t)c * 1024 + kn * 2 + kb,
                      (char*)&Bs[buf ^ 1][0] + lb);
            }
        }
        #pragma unroll
        for (int ks = 0; ks < 2; ++ks) {
            bf16x8 a = *(const bf16x8*)&As[buf][(wr * 16 + c0) * 64 + ks * 32 + g * 8];
            #pragma unroll
            for (int ni = 0; ni < 2; ++ni) {
                bf16x8 b = *(const bf16x8*)&Bs[buf][(wc * 32 + ni * 16 + c0) * 64 + ks * 32 + g * 8];
                av[ni] = __builtin_amdgcn_mfma_f32_16x16x32_bf16(a, b, av[ni], 0, 0, 0);
            }
        }
        __syncthreads();   // buf^1 writes visible; all reads of buf done
    }

    // ---- row stats: reduce over the 16 threads sharing a row, then pos/neg ----
    #pragma unroll
    for (int m = 1; m < 16; m <<= 1) {
        s += __shfl_xor(s, m); sm += __shfl_xor(sm, m); d += __shfl_xor(d, m);
    }
    double pc = 0.0, nc = 0.0;
    if ((lane & 15) == 0) {
        int h = cnt[myt];
        float pos_sum; int pos_cnt;
        if (d < 1.0) { pos_sum = sm;            pos_cnt = h;     }
        else         { pos_sum = sm - (float)d; pos_cnt = h - 1; }
        float neg_sum = s - sm;
        pc = (double)(pos_sum / (float)pos_cnt);
        nc = (double)(neg_sum / (float)(NROWS - h));
    }
    #pragma unroll
    for (int m = 1; m < 64; m <<= 1) { pc += __shfl_xor(pc, m); nc += __shfl_xor(nc, m); }

    // ---- dump logits to LDS (C-map: row = g*4+reg, col = c0) ----
    #pragma unroll
    for (int ni = 0; ni < 2; ++ni)
        #pragma unroll
        for (int r = 0; r < 4; ++r)
            P[wr * 16 + g * 4 + r][wc * 32 + ni * 16 + c0] = av[ni][r];
    __syncthreads();

    // ---- softmax / argmax / loss, 4 rows per wave ----
    float lossacc = 0.f, pracc = 0.f;
    #pragma unroll
    for (int j = 0; j < 4; ++j) {
        const int rl = w * 4 + j;
        const int tgt = trow[rl];
        float l1 = P[rl][lane], l2 = P[rl][lane + 64];
        {
            float cos1 = fminf(1.f, fmaxf(-1.f, l1));
            float cos2 = fminf(1.f, fmaxf(-1.f, l2));
            l1 = (cos1 - (lane == tgt ? BETA_F : 0.f)) * ALPHA_F;
            l2 = (cos2 - (lane + 64 == tgt ? BETA_F : 0.f)) * ALPHA_F;
            if (lane      >= NCLS) l1 = -1e30f;
            if (lane + 64 >= NCLS) l2 = -1e30f;
        }
        float m = fmaxf(l1, l2);
        #pragma unroll
        for (int dd = 1; dd < 64; dd <<= 1) m = fmaxf(m, __shfl_xor(m, dd));
        float se = (lane < NCLS ? __expf(l1 - m) : 0.f)
                 + (lane + 64 < NCLS ? __expf(l2 - m) : 0.f);
        float tval = (lane == tgt) ? l1 : ((lane + 64 == tgt) ? l2 : -1e30f);
        float bv; int bi;
        if (l2 > l1) { bv = l2; bi = lane + 64; } else { bv = l1; bi = lane; }
        #pragma unroll
        for (int dd = 1; dd < 64; dd <<= 1) {
            se += __shfl_xor(se, dd);
            tval = fmaxf(tval, __shfl_xor(tval, dd));
            float ov = __shfl_xor(bv, dd); int oi = __shfl_xor(bi, dd);
            if (ov > bv || (ov == bv && oi < bi)) { bv = ov; bi = oi; }
        }
        lossacc += (m + logf(se)) - tval;
        pracc   += (bi == tgt) ? 1.f : 0.f;
    }

    // ---- block reduce; last finishing block reduces all partials and writes d_out ----
    if (lane == 0) {
        redacc[w][0] = (double)lossacc;
        redacc[w][1] = (double)pracc;
        redacc[w][2] = pc;
        redacc[w][3] = nc;
    }
    __syncthreads();
    if (tid == 0) {
        const int bx = blockIdx.x;
        double a0 = 0.0, a1 = 0.0, a2 = 0.0, a3 = 0.0;
        #pragma unroll
        for (int ww = 0; ww < 8; ++ww) {
            a0 += redacc[ww][0]; a1 += redacc[ww][1];
            a2 += redacc[ww][2]; a3 += redacc[ww][3];
        }
        partials[bx * 4 + 0] = a0;
        partials[bx * 4 + 1] = a1;
        partials[bx * 4 + 2] = a2;
        partials[bx * 4 + 3] = a3;
        __threadfence();
        lastflag = (atomicAdd(ctr, 1u) == NBLK - 1) ? 1 : 0;
    }
    __syncthreads();
    if (lastflag && w == 0) {
        __threadfence();
        double a0 = 0.0, a1 = 0.0, a2 = 0.0, a3 = 0.0;
        for (int i = lane; i < NBLK; i += 64) {
            a0 += partials[i * 4 + 0];
            a1 += partials[i * 4 + 1];
            a2 += partials[i * 4 + 2];
            a3 += partials[i * 4 + 3];
        }
        #pragma unroll
        for (int m = 1; m < 64; m <<= 1) {
            a0 += __shfl_xor(a0, m); a1 += __shfl_xor(a1, m);
            a2 += __shfl_xor(a2, m); a3 += __shfl_xor(a3, m);
        }
        if (lane == 0) {
            out[0] = (float)(a0 / NROWS);
            out[1] = (float)(a1 / NROWS);
            out[2] = (float)(a2 / NROWS);
            out[3] = (float)(a3 / NROWS);
        }
    }
}

// ================= fallback f32 path (tiny workspace) =================
#define BM 64
#define BN 64
#define BK 32
#define LDA 68

__global__ void hist_kernel(const int* __restrict__ t, int* __restrict__ hist) {
    int i = blockIdx.x * blockDim.x + threadIdx.x;
    if (i < NROWS) atomicAdd(&hist[t[i]], 1);
}

__global__ void colnorm_kernel(const float* __restrict__ K, float* __restrict__ colinv) {
    int c = blockIdx.x;
    float s = 0.f;
    for (int k = threadIdx.x; k < EMB; k += 64) {
        float v = K[k * NCLS + c];
        s = fmaf(v, v, s);
    }
    #pragma unroll
    for (int off = 32; off > 0; off >>= 1) s += __shfl_down(s, off);
    if (threadIdx.x == 0) colinv[c] = 1.0f / sqrtf(s);
}

__global__ __launch_bounds__(256) void simred_kernel(
        const float* __restrict__ X, const int* __restrict__ T,
        float* __restrict__ S, float* __restrict__ SAME) {
    __shared__ float As[BK * LDA];
    __shared__ float Bs[BK * LDA];
    __shared__ int   trow[BM], tcol[BN];
    __shared__ float redS[BM], redSame[BM];

    const int tid = threadIdx.x;
    const int tx = tid & 15, ty = tid >> 4;
    const int i0 = blockIdx.x * BM, j0 = blockIdx.y * BN;

    if (tid < BM) {
        trow[tid] = T[i0 + tid];
        tcol[tid] = T[j0 + tid];
        redS[tid] = 0.f;
        redSame[tid] = 0.f;
    }

    float c[4][4] = {};
    for (int kk = 0; kk < EMB; kk += BK) {
        #pragma unroll
        for (int q = 0; q < 2; ++q) {
            int l  = tid * 2 + q;
            int r  = l >> 3;
            int kq = (l & 7) << 2;
            const float4 va = *(const float4*)(X + (size_t)(i0 + r) * EMB + kk + kq);
            As[(kq + 0) * LDA + r] = va.x;
            As[(kq + 1) * LDA + r] = va.y;
            As[(kq + 2) * LDA + r] = va.z;
            As[(kq + 3) * LDA + r] = va.w;
            const float4 vb = *(const float4*)(X + (size_t)(j0 + r) * EMB + kk + kq);
            Bs[(kq + 0) * LDA + r] = vb.x;
            Bs[(kq + 1) * LDA + r] = vb.y;
            Bs[(kq + 2) * LDA + r] = vb.z;
            Bs[(kq + 3) * LDA + r] = vb.w;
        }
        __syncthreads();
        #pragma unroll
        for (int k = 0; k < BK; ++k) {
            float4 a4 = *(const float4*)&As[k * LDA + ty * 4];
            float4 b4 = *(const float4*)&Bs[k * LDA + tx * 4];
            float a[4] = {a4.x, a4.y, a4.z, a4.w};
            float b[4] = {b4.x, b4.y, b4.z, b4.w};
            #pragma unroll
            for (int i = 0; i < 4; ++i)
                #pragma unroll
                for (int j = 0; j < 4; ++j)
                    c[i][j] = fmaf(a[i], b[j], c[i][j]);
        }
        __syncthreads();
    }

    #pragma unroll
    for (int i = 0; i < 4; ++i) {
        int r = ty * 4 + i;
        int tr = trow[r];
        float s = 0.f, sm = 0.f;
        #pragma unroll
        for (int j = 0; j < 4; ++j) {
            float v = c[i][j];
            s += v;
            if (tcol[tx * 4 + j] == tr) sm += v;
        }
        atomicAdd(&redS[r], s);
        atomicAdd(&redSame[r], sm);
    }
    __syncthreads();
    if (tid < BM) {
        atomicAdd(&S[i0 + tid],    redS[tid]);
        atomicAdd(&SAME[i0 + tid], redSame[tid]);
    }
}

__global__ __launch_bounds__(128) void loss_kernel(
        const float* __restrict__ X, const int* __restrict__ T,
        const float* __restrict__ K, const float* __restrict__ colinv,
        double* __restrict__ acc) {
    const int row = blockIdx.x;
    const int tid = threadIdx.x;
    __shared__ float xs[EMB];
    *(float4*)&xs[tid * 4] = *(const float4*)&X[(size_t)row * EMB + tid * 4];
    __syncthreads();

    const int tgt = T[row];
    const int c = tid;
    float logit = -1e30f;
    if (c < NCLS) {
        float d = 0.f;
        #pragma unroll 4
        for (int k = 0; k < EMB; ++k) d = fmaf(K[k * NCLS + c], xs[k], d);
        float cosv = d * colinv[c];
        cosv = fminf(1.f, fmaxf(-1.f, cosv));
        logit = (cosv - (c == tgt ? BETA_F : 0.f)) * ALPHA_F;
    }

    __shared__ float rv[128];
    __shared__ int   ri[128];
    __shared__ float Lt;
    if (c == tgt) Lt = logit;

    rv[tid] = logit;
    __syncthreads();
    #pragma unroll
    for (int s = 64; s > 0; s >>= 1) {
        if (tid < s) rv[tid] = fmaxf(rv[tid], rv[tid + s]);
        __syncthreads();
    }
    const float m = rv[0];
    __syncthreads();

    rv[tid] = (c < NCLS) ? expf(logit - m) : 0.f;
    __syncthreads();
    #pragma unroll
    for (int s = 64; s > 0; s >>= 1) {
        if (tid < s) rv[tid] += rv[tid + s];
        __syncthreads();
    }
    const float lse = m + logf(rv[0]);
    __syncthreads();

    rv[tid] = logit;
    ri[tid] = (c < NCLS) ? c : 0x7fffffff;
    __syncthreads();
    #pragma unroll
    for (int s = 64; s > 0; s >>= 1) {
        if (tid < s) {
            float vo = rv[tid + s]; int io = ri[tid + s];
            if (vo > rv[tid] || (vo == rv[tid] && io < ri[tid])) { rv[tid] = vo; ri[tid] = io; }
        }
        __syncthreads();
    }

    if (tid == 0) {
        float loss_i = lse - Lt;
        atomicAdd(&acc[0], (double)loss_i);
        atomicAdd(&acc[1], (ri[0] == tgt) ? 1.0 : 0.0);
    }
}

__global__ void finalize_kernel(
        const float* __restrict__ X, const int* __restrict__ T,
        const int* __restrict__ hist, const float* __restrict__ S,
        const float* __restrict__ SAME, double* __restrict__ acc) {
    int r = blockIdx.x * blockDim.x + threadIdx.x;
    if (r >= NROWS) return;
    const float* x = X + (size_t)r * EMB;
    double d = 0.0;
    for (int k = 0; k < EMB; ++k) d = fma((double)x[k], (double)x[k], d);
    int h = hist[T[r]];
    float same = SAME[r];
    float pos_sum; int pos_cnt;
    if (d < 1.0) { pos_sum = same;            pos_cnt = h;     }
    else         { pos_sum = same - (float)d; pos_cnt = h - 1; }
    float neg_sum = S[r] - same;
    int   neg_cnt = NROWS - h;
    atomicAdd(&acc[2], (double)(pos_sum / (float)pos_cnt));
    atomicAdd(&acc[3], (double)(neg_sum / (float)neg_cnt));
}

__global__ void out_kernel(const double* __restrict__ acc, float* __restrict__ out) {
    if (threadIdx.x == 0) {
        out[0] = (float)(acc[0] / NROWS);
        out[1] = (float)(acc[1] / NROWS);
        out[2] = (float)(acc[2] / NROWS);
        out[3] = (float)(acc[3] / NROWS);
    }
}

extern "C" void kernel_launch(void* const* d_in, const int* in_sizes, int n_in,
                              void* d_out, int out_size, void* d_ws, size_t ws_size,
                              hipStream_t stream) {
    const float* X = (const float*)d_in[0];   // [8192, 512]
    const int*   T = (const int*)d_in[1];     // [8192]
    const float* K = (const float*)d_in[2];   // [512, 98]
    float* out = (float*)d_out;               // 4 scalars

    const size_t KBT_BYTES    = (size_t)NCPAD * EMB * sizeof(unsigned short); // 128 KB
    const size_t V_BYTES      = (size_t)NCLS * EMB * sizeof(float);           // 200704 B
    const size_t BUCKET_BYTES = (size_t)NCLS * MAXPER * sizeof(int);          // 100352 B
    const size_t PART_BYTES   = (size_t)NBLK * 4 * sizeof(double);            // 8 KB
    const size_t MISC_BYTES   = 128 * sizeof(int) + 64 + 512 * sizeof(float); // cnt+ctr+usum

    if (ws_size >= KBT_BYTES + V_BYTES + BUCKET_BYTES + PART_BYTES + MISC_BYTES + 256) {
        unsigned short* KbT = (unsigned short*)d_ws;
        float*  V        = (float*)((char*)d_ws + KBT_BYTES);
        int*    bucket   = (int*)((char*)d_ws + KBT_BYTES + V_BYTES);
        double* partials = (double*)((char*)d_ws + KBT_BYTES + V_BYTES + BUCKET_BYTES);
        int*    cnt      = (int*)((char*)partials + PART_BYTES);
        unsigned int* ctr = (unsigned int*)(cnt + 128);
        float*  usum     = (float*)(ctr + 16);

        init_scatter_kernel<<<1, 1024, 0, stream>>>(T, cnt, bucket, ctr, usum);
        classv_kernel<<<800, 512, 0, stream>>>(X, K, cnt, bucket, V, usum, KbT);
        main_gemm<<<NBLK, 512, 0, stream>>>(X, KbT, T, cnt, V, usum, partials, ctr, out);
    } else {
        // fallback: f32 path (small workspace)
        const size_t FB_BYTES = sizeof(double) * 4 + sizeof(int) * NCLS
                              + sizeof(float) * (NCLS + 2 * NROWS);
        double* acc    = (double*)d_ws;
        int*    hist   = (int*)(acc + 4);
        float*  colinv = (float*)(hist + NCLS);
        float*  S      = colinv + NCLS;
        float*  SAME   = S + NROWS;

        hipMemsetAsync(d_ws, 0, FB_BYTES, stream);
        hist_kernel<<<(NROWS + 255) / 256, 256, 0, stream>>>(T, hist);
        colnorm_kernel<<<NCLS, 64, 0, stream>>>(K, colinv);
        simred_kernel<<<dim3(NROWS / BM, NROWS / BN), 256, 0, stream>>>(X, T, S, SAME);
        loss_kernel<<<NROWS, 128, 0, stream>>>(X, T, K, colinv, acc);
        finalize_kernel<<<(NROWS + 255) / 256, 256, 0, stream>>>(X, T, hist, S, SAME, acc);
        out_kernel<<<1, 64, 0, stream>>>(acc, out);
    }
}